// Round 5
// baseline (105.255 us; speedup 1.0000x reference)
//
#include <hip/hip_runtime.h>
#include <math.h>

#define B 4
#define N 4096
#define M 8192
#define C 64
#define NB 1024
#define XMIN (-64.0f)
#define INV_BW 8.0f    // bucket width 0.125
#define CUT 15.0f      // truncation at exp(-15): err ~1e-4 << 0.43 threshold
#define QG 16          // queries per group (bucket-sorted)
#define PCH 64         // points staged per chunk

__device__ __forceinline__ int bucket_of(float v) {
    int k = (int)floorf((v - XMIN) * INV_BW);
    return min(max(k, 0), NB - 1);
}

// Blocks 0..31: point histogram (B*M). Blocks 32..47: query histogram (B*N).
// Global atomics; gcp/gcq pre-zeroed via hipMemsetAsync.
__global__ __launch_bounds__(1024) void hist_kernel(
    const float* __restrict__ xz, const float* __restrict__ x,
    int* __restrict__ gcp, int* __restrict__ gcq)
{
    const int t = threadIdx.x;
    if (blockIdx.x < 32) {
        int i = blockIdx.x * 1024 + t;       // 0..B*M
        int b = i >> 13;                     // M = 8192
        atomicAdd(&gcp[b * NB + bucket_of(xz[i])], 1);
    } else {
        int i = (blockIdx.x - 32) * 1024 + t; // 0..B*N
        int b = i >> 12;                      // N = 4096
        atomicAdd(&gcq[b * NB + bucket_of(x[i])], 1);
    }
}

// Blocks 0..3: scan point hist -> bucket_start + runp. Blocks 4..7: query hist -> runq.
__global__ __launch_bounds__(NB) void scan_kernel(
    const int* __restrict__ gcp, const int* __restrict__ gcq,
    int* __restrict__ bucket_start, int* __restrict__ runp, int* __restrict__ runq)
{
    __shared__ int sc[NB];
    const int t = threadIdx.x;
    if (blockIdx.x < 4) {
        const int b = blockIdx.x;
        int cnt = gcp[b * NB + t];
        sc[t] = cnt;
        __syncthreads();
        for (int off = 1; off < NB; off <<= 1) {
            int add = (t >= off) ? sc[t - off] : 0;
            __syncthreads();
            sc[t] += add;
            __syncthreads();
        }
        int start = sc[t] - cnt;
        bucket_start[b * (NB + 1) + t] = start;
        runp[b * NB + t] = start;
        if (t == NB - 1) bucket_start[b * (NB + 1) + NB] = sc[t];  // == M
    } else {
        const int b = blockIdx.x - 4;
        int cnt = gcq[b * NB + t];
        sc[t] = cnt;
        __syncthreads();
        for (int off = 1; off < NB; off <<= 1) {
            int add = (t >= off) ? sc[t - off] : 0;
            __syncthreads();
            sc[t] += add;
            __syncthreads();
        }
        runq[b * NB + t] = sc[t] - cnt;
    }
}

// Blocks 0..511: fused scatter+transpose. Each block owns a 64-point tile of z:
// compute each point's sorted slot (global atomic on runp), write xs[slot] and
// the z row zs[slot][0..63] (contiguous 256B row writes).
// Blocks 512..527: scatter queries -> qcs/qis (sorted order).
__global__ __launch_bounds__(1024) void permute_kernel(
    const float* __restrict__ xz, const float* __restrict__ z,
    const float* __restrict__ x,
    int* __restrict__ runp, int* __restrict__ runq,
    float* __restrict__ xs, float* __restrict__ zs,
    float* __restrict__ qcs, int* __restrict__ qis)
{
    const int t = threadIdx.x;
    if (blockIdx.x < 512) {
        const int b  = blockIdx.x >> 7;       // 128 tiles per batch
        const int m0 = (blockIdx.x & 127) * 64;
        __shared__ float tile[64][65];
        __shared__ int slot[64];
        const int m = t & 63;
        for (int c = t >> 6; c < 64; c += 16)          // coalesced in m
            tile[c][m] = z[((size_t)b * C + c) * M + m0 + m];
        if (t < 64) {
            float v = xz[b * M + m0 + t];
            int s = atomicAdd(&runp[b * NB + bucket_of(v)], 1);
            slot[t] = s;
            xs[b * M + s] = v;
        }
        __syncthreads();
        // write rows: thread t -> local row j, float4 chunk c4
        const int j  = t >> 4;
        const int c4 = t & 15;
        float4 v4 = make_float4(tile[c4 * 4 + 0][j], tile[c4 * 4 + 1][j],
                                tile[c4 * 4 + 2][j], tile[c4 * 4 + 3][j]);
        ((float4*)zs)[((size_t)b * M + slot[j]) * 16 + c4] = v4;
    } else {
        int i = (blockIdx.x - 512) * 1024 + t;   // 0..B*N
        int b = i >> 12;
        int n = i & (N - 1);
        float v = x[i];
        int s = atomicAdd(&runq[b * NB + bucket_of(v)], 1);
        qcs[b * N + s] = v;
        qis[b * N + s] = n;
    }
}

// One block per group of QG=16 sorted queries; 4 waves, each owns 4 queries.
// Window is a CONTIGUOUS slot range [s0,s1): zs rows stream direct-to-LDS via
// coalesced global_load_lds; weights lane-parallel (lanes=points), overlapped
// with the staging loads; dot phase is pure fmac on LDS.
__global__ __launch_bounds__(256) void gather_kernel(
    const float* __restrict__ log_scale,
    const int* __restrict__ bucket_start,
    const float* __restrict__ xs,
    const float* __restrict__ qcs,
    const int* __restrict__ qis,
    const float* __restrict__ zs,      // [B*M + slack][C] sorted rows
    float* __restrict__ out)           // [B][N][C]
{
    const int t    = threadIdx.x;
    const int lane = t & 63;
    const int w    = t >> 6;            // wave 0..3
    const int g  = blockIdx.x;
    const int b  = g >> 8;              // 256 groups per batch
    const int g0 = (g & 255) * QG;

    __shared__ __align__(16) float zr[PCH][C];    // 16 KB staged z rows
    __shared__ __align__(16) float wl[QG][PCH];   // 4 KB weights [q][p]
    __shared__ float qc[QG];
    __shared__ int   qi[QG];

    const float ls   = log_scale[0];
    const float coef = -0.5f * __expf(-2.0f * ls);   // negative
    const float R    = sqrtf(CUT / (-coef));

    if (t < QG) {
        qc[t] = qcs[b * N + g0 + t];
        qi[t] = qis[b * N + g0 + t];
    }
    __syncthreads();

    float xmin = qc[0], xmax = qc[0];
    #pragma unroll
    for (int j = 1; j < QG; ++j) {          // within-bucket order is arbitrary
        xmin = fminf(xmin, qc[j]);
        xmax = fmaxf(xmax, qc[j]);
    }
    const int s0 = bucket_start[b * (NB + 1) + bucket_of(xmin - R)];
    const int s1 = bucket_start[b * (NB + 1) + bucket_of(xmax + R) + 1];

    const float q0 = qc[w * 4 + 0], q1 = qc[w * 4 + 1];
    const float q2 = qc[w * 4 + 2], q3 = qc[w * 4 + 3];
    float a0 = 0.f, a1 = 0.f, a2 = 0.f, a3 = 0.f;

    const float*  xsb = xs + b * M;
    const float4* zs4 = (const float4*)zs + (size_t)b * M * 16;

    for (int cs = s0; cs < s1; cs += PCH) {
        const int cnt = min(PCH, s1 - cs);
        __syncthreads();                 // zr free from previous chunk
        // stage 64 contiguous zs rows -> zr (wave w, round r covers rows
        // r*16+w*4 .. +3; lane supplies 16B; fully coalesced global reads).
        #pragma unroll
        for (int r = 0; r < 4; ++r) {
            const float4* gp = zs4 + ((size_t)cs) * 16 + r * 256 + w * 64 + lane;
            float* lp = &zr[r * 16 + w * 4][0];           // wave-uniform base
            __builtin_amdgcn_global_load_lds(
                (const __attribute__((address_space(1))) void*)gp,
                (__attribute__((address_space(3))) void*)lp, 16, 0, 0);
        }
        // overlapped: wave-local weights, lanes = points (coords from global,
        // wave-coalesced 256B, L1-hot; slack-backed so unguarded is safe)
        {
            const float pcr   = xsb[cs + lane];
            const bool  valid = (cs + lane) < s1;
            float d0 = q0 - pcr, d1 = q1 - pcr, d2 = q2 - pcr, d3 = q3 - pcr;
            wl[w * 4 + 0][lane] = valid ? __expf(coef * d0 * d0) : 0.0f;
            wl[w * 4 + 1][lane] = valid ? __expf(coef * d1 * d1) : 0.0f;
            wl[w * 4 + 2][lane] = valid ? __expf(coef * d2 * d2) : 0.0f;
            wl[w * 4 + 3][lane] = valid ? __expf(coef * d3 * d3) : 0.0f;
        }
        __syncthreads();                 // zr staged (barrier drains vmcnt)
        for (int p = 0; p < cnt; p += 4) {
            float zv0 = zr[p + 0][lane];
            float zv1 = zr[p + 1][lane];
            float zv2 = zr[p + 2][lane];
            float zv3 = zr[p + 3][lane];
            const float4 wa = *(const float4*)&wl[w * 4 + 0][p];
            const float4 wb = *(const float4*)&wl[w * 4 + 1][p];
            const float4 wc = *(const float4*)&wl[w * 4 + 2][p];
            const float4 wd = *(const float4*)&wl[w * 4 + 3][p];
            a0 = fmaf(wa.x, zv0, a0); a0 = fmaf(wa.y, zv1, a0);
            a0 = fmaf(wa.z, zv2, a0); a0 = fmaf(wa.w, zv3, a0);
            a1 = fmaf(wb.x, zv0, a1); a1 = fmaf(wb.y, zv1, a1);
            a1 = fmaf(wb.z, zv2, a1); a1 = fmaf(wb.w, zv3, a1);
            a2 = fmaf(wc.x, zv0, a2); a2 = fmaf(wc.y, zv1, a2);
            a2 = fmaf(wc.z, zv2, a2); a2 = fmaf(wc.w, zv3, a2);
            a3 = fmaf(wd.x, zv0, a3); a3 = fmaf(wd.y, zv1, a3);
            a3 = fmaf(wd.z, zv2, a3); a3 = fmaf(wd.w, zv3, a3);
        }
    }

    out[((size_t)b * N + qi[w * 4 + 0]) * C + lane] = a0;
    out[((size_t)b * N + qi[w * 4 + 1]) * C + lane] = a1;
    out[((size_t)b * N + qi[w * 4 + 2]) * C + lane] = a2;
    out[((size_t)b * N + qi[w * 4 + 3]) * C + lane] = a3;
}

extern "C" void kernel_launch(void* const* d_in, const int* in_sizes, int n_in,
                              void* d_out, int out_size, void* d_ws, size_t ws_size,
                              hipStream_t stream) {
    const float* xz = (const float*)d_in[0];  // [B,M,1]
    const float* z  = (const float*)d_in[1];  // [B,C,M]
    const float* x  = (const float*)d_in[2];  // [B,N,1]
    const float* ls = (const float*)d_in[3];  // scalar
    float* out = (float*)d_out;               // [B,N,C]

    char* ws = (char*)d_ws;
    size_t off = 0;
    auto alloc = [&](size_t bytes) { void* p = ws + off; off += (bytes + 255) & ~size_t(255); return p; };

    // +64 rows / +64 floats of slack: gather's unguarded chunk tail reads
    float* zs  = (float*)alloc(((size_t)B * M + 64) * C * sizeof(float));  // ~8.4 MB
    float* xs  = (float*)alloc(((size_t)B * M + 64) * sizeof(float));
    float* qcs = (float*)alloc((size_t)B * N * sizeof(float));
    int*   qis = (int*)alloc((size_t)B * N * sizeof(int));
    int*   bst = (int*)alloc((size_t)B * (NB + 1) * sizeof(int));
    int*   gc  = (int*)alloc((size_t)2 * B * NB * sizeof(int));  // gcp|gcq contiguous
    int*   gcp = gc;
    int*   gcq = gc + B * NB;
    int*   runp = (int*)alloc((size_t)B * NB * sizeof(int));
    int*   runq = (int*)alloc((size_t)B * NB * sizeof(int));

    hipMemsetAsync(gc, 0, (size_t)2 * B * NB * sizeof(int), stream);
    hist_kernel<<<48, 1024, 0, stream>>>(xz, x, gcp, gcq);
    scan_kernel<<<8, NB, 0, stream>>>(gcp, gcq, bst, runp, runq);
    permute_kernel<<<528, 1024, 0, stream>>>(xz, z, x, runp, runq, xs, zs, qcs, qis);
    gather_kernel<<<B * (N / QG), 256, 0, stream>>>(ls, bst, xs, qcs, qis, zs, out);
}